// Round 1
// baseline (170.244 us; speedup 1.0000x reference)
//
#include <hip/hip_runtime.h>
#include <hip/hip_bf16.h>

// DWT 2D low-pass = separable 4-tap stride-2 stencil:
//   out[p,q] = sum_{i,j} f[i]*f[j] * x[2p-1+i, 2q-1+j], OOB -> 0
// f[j] = matrix_h[1][1+j] (db2 reconstruction low-pass taps).

#define DWT_H 512
#define DWT_W 512
#define DWT_PH 256
#define DWT_PW 256
#define DWT_P 8   // p-outputs per thread

__global__ __launch_bounds__(256)
void dwt2d_low_kernel(const float* __restrict__ x,
                      const float* __restrict__ mh,
                      float* __restrict__ out)
{
    const int q  = threadIdx.x;            // 0..255, lane-consecutive -> coalesced
    const int p0 = blockIdx.x * DWT_P;     // base output row
    const int bc = blockIdx.y;             // fused batch*channel

    // filter taps: matrix_h[1][1..4] == band_low[0..3]
    const float f0 = mh[DWT_W + 1];
    const float f1 = mh[DWT_W + 2];
    const float f2 = mh[DWT_W + 3];
    const float f3 = mh[DWT_W + 4];

    const float* xi = x   + (size_t)bc * DWT_H * DWT_W;
    float*       yo = out + (size_t)bc * DWT_PH * DWT_PW;

    const int  c0     = 2 * q;                 // aligned base column (float2)
    const bool has_m1 = (q > 0);               // col 2q-1 exists
    const bool has_p2 = (c0 + 2 < DWT_W);      // col 2q+2 exists

    float rv[2 * DWT_P + 2];                   // column-filtered values per input row

    #pragma unroll
    for (int r = 0; r < 2 * DWT_P + 2; ++r) {
        const int gr = 2 * p0 - 1 + r;         // global input row (wave-uniform)
        float xm1 = 0.f, x0 = 0.f, x1 = 0.f, xp2 = 0.f;
        if (gr >= 0 && gr < DWT_H) {           // uniform branch (blockIdx-only)
            const float* row = xi + (size_t)gr * DWT_W;
            const float2 v = *reinterpret_cast<const float2*>(row + c0);
            x0 = v.x; x1 = v.y;
            if (has_m1) xm1 = row[c0 - 1];
            if (has_p2) xp2 = row[c0 + 2];
        }
        rv[r] = f0 * xm1 + f1 * x0 + f2 * x1 + f3 * xp2;
    }

    #pragma unroll
    for (int pl = 0; pl < DWT_P; ++pl) {
        const float acc = f0 * rv[2 * pl]     + f1 * rv[2 * pl + 1]
                        + f2 * rv[2 * pl + 2] + f3 * rv[2 * pl + 3];
        yo[(size_t)(p0 + pl) * DWT_PW + q] = acc;
    }
}

extern "C" void kernel_launch(void* const* d_in, const int* in_sizes, int n_in,
                              void* d_out, int out_size, void* d_ws, size_t ws_size,
                              hipStream_t stream)
{
    const float* x  = (const float*)d_in[0];   // (B,C,512,512) fp32
    const float* mh = (const float*)d_in[1];   // (256,512) fp32
    float* out      = (float*)d_out;           // (B,C,256,256) fp32

    const int bc = in_sizes[0] / (DWT_H * DWT_W);   // B*C = 512

    dim3 grid(DWT_PH / DWT_P, bc);
    dim3 block(256);
    dwt2d_low_kernel<<<grid, block, 0, stream>>>(x, mh, out);
}

// Round 2
// 162.460 us; speedup vs baseline: 1.0479x; 1.0479x over previous
//
#include <hip/hip_runtime.h>
#include <hip/hip_bf16.h>

// DWT 2D low-pass = separable 4-tap stride-2 stencil:
//   out[p,q] = sum_{i,j} f[i]*f[j] * x[2p-1+i, 2q-1+j], OOB -> 0
// f[j] = matrix_h[1][1+j] (db2 reconstruction low-pass taps).
//
// Strip kernel: block = 256 threads (one output column q each); each block
// produces a 64-row output strip using a rolling 4-row column-filtered
// window (rv0..rv3) so every input row is fetched exactly once per strip.
// Horizontal neighbors come from wave shuffles of the aligned float2 load;
// only wave-boundary lanes fall back to a predicated scalar load.

#define DWT_H 512
#define DWT_W 512
#define DWT_PH 256
#define DWT_PW 256
#define DWT_STRIP 64   // output rows per block

__device__ __forceinline__ float row_filter(const float* __restrict__ row,
                                            int q, bool valid,
                                            float f0, float f1, float f2, float f3)
{
    float vx = 0.f, vy = 0.f;
    if (valid) {                       // uniform branch (row validity)
        const float2 v = *reinterpret_cast<const float2*>(row + 2 * q);
        vx = v.x; vy = v.y;
    }
    // x[2q-1] lives in lane q-1's vy; x[2q+2] in lane q+1's vx.
    float up = __shfl_up(vy, 1, 64);
    float dn = __shfl_down(vx, 1, 64);
    const int l = q & 63;
    if (l == 0)  up = (valid && q > 0)          ? row[2 * q - 1] : 0.f;  // 1 lane/wave
    if (l == 63) dn = (valid && q < DWT_PW - 1) ? row[2 * q + 2] : 0.f;  // 1 lane/wave
    return f0 * up + f1 * vx + f2 * vy + f3 * dn;
}

__global__ __launch_bounds__(256, 8)
void dwt2d_low_kernel(const float* __restrict__ x,
                      const float* __restrict__ mh,
                      float* __restrict__ out)
{
    const int q     = threadIdx.x;        // 0..255, coalesced
    const int strip = blockIdx.x;         // 0..3
    const int bc    = blockIdx.y;         // batch*channel
    const int p0    = strip * DWT_STRIP;

    // filter taps: matrix_h[1][1..4] == band_low[0..3]
    const float f0 = mh[DWT_W + 1];
    const float f1 = mh[DWT_W + 2];
    const float f2 = mh[DWT_W + 3];
    const float f3 = mh[DWT_W + 4];

    const float* xi = x + (size_t)bc * DWT_H * DWT_W;
    float* yo = out + (size_t)bc * DWT_PH * DWT_PW + (size_t)p0 * DWT_PW + q;

    // rolling window: rows 2p-1, 2p, 2p+1, 2p+2
    float rv0 = row_filter(xi + (ptrdiff_t)(2 * p0 - 1) * DWT_W, q, p0 > 0, f0, f1, f2, f3);
    float rv1 = row_filter(xi + (ptrdiff_t)(2 * p0) * DWT_W,     q, true,   f0, f1, f2, f3);

    #pragma unroll 4
    for (int i = 0; i < DWT_STRIP; ++i) {
        const int p  = p0 + i;
        const int g2 = 2 * p + 2;
        const float rv2 = row_filter(xi + (ptrdiff_t)(2 * p + 1) * DWT_W, q, true,        f0, f1, f2, f3);
        const float rv3 = row_filter(xi + (ptrdiff_t)g2 * DWT_W,          q, g2 < DWT_H,  f0, f1, f2, f3);
        yo[(size_t)i * DWT_PW] = f0 * rv0 + f1 * rv1 + f2 * rv2 + f3 * rv3;
        rv0 = rv2;
        rv1 = rv3;
    }
}

extern "C" void kernel_launch(void* const* d_in, const int* in_sizes, int n_in,
                              void* d_out, int out_size, void* d_ws, size_t ws_size,
                              hipStream_t stream)
{
    const float* x  = (const float*)d_in[0];   // (B,C,512,512) fp32
    const float* mh = (const float*)d_in[1];   // (256,512) fp32
    float* out      = (float*)d_out;           // (B,C,256,256) fp32

    const int bc = in_sizes[0] / (DWT_H * DWT_W);   // B*C = 512

    dim3 grid(DWT_PH / DWT_STRIP, bc);             // 4 x 512 = 2048 blocks = 8/CU
    dim3 block(256);
    dwt2d_low_kernel<<<grid, block, 0, stream>>>(x, mh, out);
}

// Round 3
// 140.894 us; speedup vs baseline: 1.2083x; 1.1531x over previous
//
#include <hip/hip_runtime.h>
#include <hip/hip_bf16.h>

// DWT 2D low-pass = separable 4-tap stride-2 stencil:
//   out[p,q] = sum_{i,j} f[i]*f[j] * x[2p-1+i, 2q-1+j], OOB -> 0
// f[j] = matrix_h[1][1+j] (db2 reconstruction low-pass taps).
//
// One wave spans the full 512-col input row: lane l loads cols 8l..8l+7 via
// two aligned float4 loads and produces output cols 4l..4l+3 (float4 store).
// Horizontal halo = 1 shfl_up + 1 shfl_down per input row; wave edge ==
// image edge, so boundary handling is two cndmasks (no divergence, no
// scalar edge loads). Each wave owns a 32-output-row strip with a rolling
// float4 column-filtered window (rv0..rv3): every input row loaded once
// per strip (+3% halo).

#define DWT_H 512
#define DWT_W 512
#define DWT_PH 256
#define DWT_PW 256
#define WAVE_S 32   // output rows per wave

__device__ __forceinline__ float4 colf(const float* __restrict__ p, int lane, bool valid,
                                       float f0, float f1, float f2, float f3)
{
    float4 a = make_float4(0.f, 0.f, 0.f, 0.f);
    float4 b = make_float4(0.f, 0.f, 0.f, 0.f);
    if (valid) {                                   // wave-uniform branch
        a = *reinterpret_cast<const float4*>(p);
        b = *reinterpret_cast<const float4*>(p + 4);
    }
    float left  = __shfl_up(b.w, 1, 64);           // x[8l-1]
    float right = __shfl_down(a.x, 1, 64);         // x[8l+8]
    if (lane == 0)  left  = 0.f;                   // image left edge
    if (lane == 63) right = 0.f;                   // image right edge
    float4 r;
    r.x = f0 * left + f1 * a.x + f2 * a.y + f3 * a.z;
    r.y = f0 * a.y  + f1 * a.z + f2 * a.w + f3 * b.x;
    r.z = f0 * a.w  + f1 * b.x + f2 * b.y + f3 * b.z;
    r.w = f0 * b.y  + f1 * b.z + f2 * b.w + f3 * right;
    return r;
}

__global__ __launch_bounds__(256, 4)
void dwt2d_low_kernel(const float* __restrict__ x,
                      const float* __restrict__ mh,
                      float* __restrict__ out)
{
    const int lane = threadIdx.x & 63;
    const int wv   = threadIdx.x >> 6;                     // 0..3
    const int bc   = blockIdx.y;
    const int p0   = blockIdx.x * (4 * WAVE_S) + wv * WAVE_S;

    // filter taps: matrix_h[1][1..4] == band_low[0..3]
    const float f0 = mh[DWT_W + 1];
    const float f1 = mh[DWT_W + 2];
    const float f2 = mh[DWT_W + 3];
    const float f3 = mh[DWT_W + 4];

    const float* xi = x + (size_t)bc * DWT_H * DWT_W + 8 * lane;
    float* yo = out + (size_t)bc * DWT_PH * DWT_PW
                    + (size_t)p0 * DWT_PW + 4 * lane;

    // rolling window: input rows 2p-1, 2p, 2p+1, 2p+2 (column-filtered)
    float4 rv0 = colf(xi + (ptrdiff_t)(2 * p0 - 1) * DWT_W, lane, p0 > 0, f0, f1, f2, f3);
    float4 rv1 = colf(xi + (ptrdiff_t)(2 * p0) * DWT_W,     lane, true,   f0, f1, f2, f3);

    #pragma unroll 2
    for (int i = 0; i < WAVE_S; ++i) {
        const int p  = p0 + i;
        const int g2 = 2 * p + 2;
        float4 rv2 = colf(xi + (ptrdiff_t)(2 * p + 1) * DWT_W, lane, true,         f0, f1, f2, f3);
        float4 rv3 = colf(xi + (ptrdiff_t)g2 * DWT_W,          lane, g2 < DWT_H,   f0, f1, f2, f3);
        float4 o;
        o.x = f0 * rv0.x + f1 * rv1.x + f2 * rv2.x + f3 * rv3.x;
        o.y = f0 * rv0.y + f1 * rv1.y + f2 * rv2.y + f3 * rv3.y;
        o.z = f0 * rv0.z + f1 * rv1.z + f2 * rv2.z + f3 * rv3.z;
        o.w = f0 * rv0.w + f1 * rv1.w + f2 * rv2.w + f3 * rv3.w;
        *reinterpret_cast<float4*>(yo + (size_t)i * DWT_PW) = o;
        rv0 = rv2;
        rv1 = rv3;
    }
}

extern "C" void kernel_launch(void* const* d_in, const int* in_sizes, int n_in,
                              void* d_out, int out_size, void* d_ws, size_t ws_size,
                              hipStream_t stream)
{
    const float* x  = (const float*)d_in[0];   // (B,C,512,512) fp32
    const float* mh = (const float*)d_in[1];   // (256,512) fp32
    float* out      = (float*)d_out;           // (B,C,256,256) fp32

    const int bc = in_sizes[0] / (DWT_H * DWT_W);   // B*C = 512

    dim3 grid(DWT_PH / (4 * WAVE_S), bc);           // 2 x 512 = 1024 blocks
    dim3 block(256);
    dwt2d_low_kernel<<<grid, block, 0, stream>>>(x, mh, out);
}

// Round 5
// 138.783 us; speedup vs baseline: 1.2267x; 1.0152x over previous
//
#include <hip/hip_runtime.h>
#include <hip/hip_bf16.h>

// DWT 2D low-pass = separable 4-tap stride-2 stencil:
//   out[p,q] = sum_{i,j} f[i]*f[j] * x[2p-1+i, 2q-1+j], OOB -> 0
// f[j] = matrix_h[1][1+j] (db2 reconstruction low-pass taps).
//
// One wave spans the full 512-col input row: lane l loads cols 8l..8l+7 via
// two aligned float4 loads, produces output cols 4l..4l+3 (one float4 NT
// store). Horizontal halo = 1 shfl_up + 1 shfl_down per input row.
// Vertical edges handled with clamped row addresses + multiplicative masks
// (no conditional loads -> fully pipelineable). Each wave owns a 16-row
// output strip with a rolling column-filtered window; 2048 blocks = 8/CU,
// launch_bounds(256,8) keeps VGPR<=64 -> 32 waves/CU for latency hiding.

#define DWT_H 512
#define DWT_W 512
#define DWT_PH 256
#define DWT_PW 256
#define WAVE_S 16   // output rows per wave

typedef float f32x4 __attribute__((ext_vector_type(4)));  // NT-store-legal vec

__device__ __forceinline__ float4 colf(const float* __restrict__ p, int lane,
                                       float f0, float f1, float f2, float f3)
{
    const float4 a = *reinterpret_cast<const float4*>(p);
    const float4 b = *reinterpret_cast<const float4*>(p + 4);
    float left  = __shfl_up(b.w, 1, 64);           // x[8l-1]
    float right = __shfl_down(a.x, 1, 64);         // x[8l+8]
    if (lane == 0)  left  = 0.f;                   // image left edge
    if (lane == 63) right = 0.f;                   // image right edge
    float4 r;
    r.x = f0 * left + f1 * a.x + f2 * a.y + f3 * a.z;
    r.y = f0 * a.y  + f1 * a.z + f2 * a.w + f3 * b.x;
    r.z = f0 * a.w  + f1 * b.x + f2 * b.y + f3 * b.z;
    r.w = f0 * b.y  + f1 * b.z + f2 * b.w + f3 * right;
    return r;
}

__global__ __launch_bounds__(256, 8)
void dwt2d_low_kernel(const float* __restrict__ x,
                      const float* __restrict__ mh,
                      float* __restrict__ out)
{
    const int lane = threadIdx.x & 63;
    const int wv   = threadIdx.x >> 6;                     // 0..3
    const int bc   = blockIdx.y;
    const int p0   = blockIdx.x * (4 * WAVE_S) + wv * WAVE_S;

    // filter taps: matrix_h[1][1..4] == band_low[0..3] (uniform -> SGPR)
    const float f0 = mh[DWT_W + 1];
    const float f1 = mh[DWT_W + 2];
    const float f2 = mh[DWT_W + 3];
    const float f3 = mh[DWT_W + 4];

    const float* xi = x + (size_t)bc * DWT_H * DWT_W + 8 * lane;
    float* yo = out + (size_t)bc * DWT_PH * DWT_PW
                    + (size_t)p0 * DWT_PW + 4 * lane;

    // prologue rows 2p0-1 (clamped+masked) and 2p0 (always valid)
    const int   gr0  = 2 * p0 - 1;
    const float mtop = (gr0 >= 0) ? 1.f : 0.f;
    float4 rv0 = colf(xi + (ptrdiff_t)max(gr0, 0) * DWT_W, lane, f0, f1, f2, f3);
    rv0.x *= mtop; rv0.y *= mtop; rv0.z *= mtop; rv0.w *= mtop;
    float4 rv1 = colf(xi + (ptrdiff_t)(2 * p0) * DWT_W, lane, f0, f1, f2, f3);

    #pragma unroll 4
    for (int i = 0; i < WAVE_S; ++i) {
        const int p  = p0 + i;
        const int g2 = 2 * p + 2;                          // ==512 only at p==255
        const float mb = (g2 < DWT_H) ? 1.f : 0.f;
        float4 rv2 = colf(xi + (ptrdiff_t)(2 * p + 1) * DWT_W, lane, f0, f1, f2, f3);
        float4 rv3 = colf(xi + (ptrdiff_t)min(g2, DWT_H - 1) * DWT_W, lane, f0, f1, f2, f3);
        rv3.x *= mb; rv3.y *= mb; rv3.z *= mb; rv3.w *= mb;
        f32x4 o;
        o.x = f0 * rv0.x + f1 * rv1.x + f2 * rv2.x + f3 * rv3.x;
        o.y = f0 * rv0.y + f1 * rv1.y + f2 * rv2.y + f3 * rv3.y;
        o.z = f0 * rv0.z + f1 * rv1.z + f2 * rv2.z + f3 * rv3.z;
        o.w = f0 * rv0.w + f1 * rv1.w + f2 * rv2.w + f3 * rv3.w;
        __builtin_nontemporal_store(o, reinterpret_cast<f32x4*>(yo + (size_t)i * DWT_PW));
        rv0 = rv2;
        rv1 = rv3;
    }
}

extern "C" void kernel_launch(void* const* d_in, const int* in_sizes, int n_in,
                              void* d_out, int out_size, void* d_ws, size_t ws_size,
                              hipStream_t stream)
{
    const float* x  = (const float*)d_in[0];   // (B,C,512,512) fp32
    const float* mh = (const float*)d_in[1];   // (256,512) fp32
    float* out      = (float*)d_out;           // (B,C,256,256) fp32

    const int bc = in_sizes[0] / (DWT_H * DWT_W);   // B*C = 512

    dim3 grid(DWT_PH / (4 * WAVE_S), bc);           // 4 x 512 = 2048 blocks = 8/CU
    dim3 block(256);
    dwt2d_low_kernel<<<grid, block, 0, stream>>>(x, mh, out);
}